// Round 3
// baseline (832.820 us; speedup 1.0000x reference)
//
#include <hip/hip_runtime.h>
#include <hip/hip_cooperative_groups.h>
#include <math.h>

namespace cg = cooperative_groups;

#define N_NODES 10000
#define N_EDGES 640000
#define DIM     128
#define NCLS    10
#define NGRAPH  64
#define NB      157    // buckets of 64 nodes (dst>>6)
#define BCAP    4608   // bucket capacity; bucket ~Poisson(4076), 8 sigma pad
#define EPB     4000   // edges per bin-unit (160 units)
#define NPB     8      // nodes per layer-unit (1250 units)
#define NLU     (N_NODES / NPB)

typedef unsigned int uint32;
typedef unsigned short ushort16;

struct BinSh { uint32 pk[EPB]; int cntS[NB]; int offS[NB]; int curS[NB]; int gposS[NB]; };
struct BBSh  { ushort16 adj[64 * 128]; int cnt2[64]; };
struct LySh  { float Xs[NPB * DIM]; };
union AllSh  { BinSh bin; BBSh bb; LySh ly; };   // 18512 B

__device__ __forceinline__ ushort16 f32_to_bf16_rne(float f) {
    uint32 u = __float_as_uint(f);
    u = (u + 0x7fffu + ((u >> 16) & 1u)) >> 16;   // round-to-nearest-even
    return (ushort16)u;
}
__device__ __forceinline__ float blo(uint32 x) { return __uint_as_float(x << 16); }
__device__ __forceinline__ float bhi(uint32 x) { return __uint_as_float(x & 0xffff0000u); }

// ---------------- unit: layer-1 GEMM (16 rows) ----------------
__device__ __forceinline__ void gemm1_unit(int u, const float* __restrict__ X,
                                           const float* __restrict__ W,
                                           ushort16* __restrict__ Gh) {
    int c    = threadIdx.x & 127;
    int rg   = threadIdx.x >> 7;
    int row0 = u * 16 + rg * 8;
    const float* xb = X + row0 * DIM;
    float acc[8] = {0.f, 0.f, 0.f, 0.f, 0.f, 0.f, 0.f, 0.f};
    for (int k = 0; k < DIM; k += 4) {
        float w0 = W[(k + 0) * DIM + c];
        float w1 = W[(k + 1) * DIM + c];
        float w2 = W[(k + 2) * DIM + c];
        float w3 = W[(k + 3) * DIM + c];
#pragma unroll
        for (int r = 0; r < 8; r++) {
            float4 xv = *(const float4*)(xb + r * DIM + k);
            acc[r] += xv.x * w0 + xv.y * w1 + xv.z * w2 + xv.w * w3;
        }
    }
#pragma unroll
    for (int r = 0; r < 8; r++)
        Gh[(row0 + r) * DIM + c] = f32_to_bf16_rne(acc[r]);
}

// ---------------- unit: edge binning (4000 edges) ----------------
__device__ __forceinline__ void bin_unit(int ab, const int* __restrict__ src,
                                         const int* __restrict__ dst,
                                         int* __restrict__ gcursor,
                                         uint32* __restrict__ bins, BinSh& B) {
    int tid = threadIdx.x;
    for (int i = tid; i < NB; i += 256) B.cntS[i] = 0;
    __syncthreads();

    int base = ab * EPB;
    uint32 pr[16];
#pragma unroll
    for (int it = 0; it < 16; it++) {
        int i = it * 256 + tid;
        uint32 p = 0xffffffffu;
        if (i < EPB) {
            int e = base + i;
            p = ((uint32)dst[e] << 16) | (uint32)src[e];
            atomicAdd(&B.cntS[p >> 22], 1);     // p>>22 == dst>>6
        }
        pr[it] = p;
    }
    __syncthreads();

    // exclusive scan of cntS by wave 0 (3 rounds of 64)
    if (tid < 64) {
        int carry = 0;
        for (int r = 0; r < 3; r++) {
            int idx = r * 64 + tid;
            int v = (idx < NB) ? B.cntS[idx] : 0;
            int inc = v;
#pragma unroll
            for (int o = 1; o < 64; o <<= 1) {
                int uu = __shfl_up(inc, o, 64);
                if (tid >= o) inc += uu;
            }
            if (idx < NB) { B.offS[idx] = inc - v + carry; B.curS[idx] = inc - v + carry; }
            carry += __shfl(inc, 63, 64);
        }
    }
    __syncthreads();

    // relocate into LDS so global writes are sequential runs
#pragma unroll
    for (int it = 0; it < 16; it++) {
        uint32 p = pr[it];
        if (p != 0xffffffffu) {
            int b = p >> 22;
            B.pk[atomicAdd(&B.curS[b], 1)] = p;
        }
    }
    __syncthreads();

    if (tid < NB) B.gposS[tid] = atomicAdd(&gcursor[tid], B.cntS[tid]);
    __syncthreads();

#pragma unroll
    for (int it = 0; it < 16; it++) {
        int i = it * 256 + tid;
        if (i < EPB) {
            uint32 uv = B.pk[i];
            int b = uv >> 22;
            int gp = B.gposS[b] + (i - B.offS[b]);
            if (gp < BCAP) bins[b * BCAP + gp] = uv;
        }
    }
}

__device__ __forceinline__ void zero_xr_unit(float* __restrict__ xr) {
    float4 z = make_float4(0.f, 0.f, 0.f, 0.f);
    for (int j = threadIdx.x; j < NGRAPH * DIM / 4; j += 256)
        ((float4*)xr)[j] = z;
}

// ---------------- unit: bucket -> padded adjacency ----------------
__device__ __forceinline__ void binB_unit(int b, const int* __restrict__ gcursor,
                                          const uint32* __restrict__ bins,
                                          ushort16* __restrict__ col,
                                          int* __restrict__ deg,
                                          float* __restrict__ dis, BBSh& S) {
    int tid = threadIdx.x;
    if (tid < 64) S.cnt2[tid] = 0;
    __syncthreads();
    int tc = gcursor[b];
    if (tc > BCAP) tc = BCAP;
    const uint32* bb = bins + b * BCAP;
    for (int i = tid; i < tc; i += 256) {
        uint32 u = bb[i];
        int local = (u >> 16) & 63;
        int r = atomicAdd(&S.cnt2[local], 1);
        if (r < 128) S.adj[(local << 7) + r] = (ushort16)(u & 0xffffu);
    }
    __syncthreads();
    uint4* dstp = (uint4*)(col + (size_t)b * 64 * 128);
    const uint4* srcp = (const uint4*)S.adj;
    for (int j = tid; j < 1024; j += 256) dstp[j] = srcp[j];
    if (tid < 64) {
        int node = b * 64 + tid;          // arrays padded to 10240
        int c = S.cnt2[tid] < 128 ? S.cnt2[tid] : 128;
        deg[node] = c;
        dis[node] = rsqrtf((float)c + 1.0f);
    }
}

// ---------------- agg (16-lane x 16B gathers) -> LDS ----------------
template <bool SCALED_IN>
__device__ __forceinline__ void agg_to_lds(int u, const ushort16* __restrict__ Gh,
                                           const int* __restrict__ deg,
                                           const ushort16* __restrict__ col,
                                           const float* __restrict__ dis,
                                           float* __restrict__ Xs) {
    int tid  = threadIdx.x;
    int wave = tid >> 6;
    int lane = tid & 63;
    int grp  = lane >> 4;       // 0..3 : which edge of the 4-per-load
    int sl   = lane & 15;       // 0..15: 16B slice of the 256B row
    const uint32* g32 = (const uint32*)Gh;
    const uint32* gp  = g32 + (sl << 2);   // +sl*16B within a row

#pragma unroll
    for (int i = 0; i < 2; i++) {
        int vr = wave * 2 + i;              // local node 0..7
        int v  = u * NPB + vr;
        int dv = deg[v];
        uint32 colpack = ((const uint32*)(col + ((size_t)v << 7)))[lane];
        float acc[8];
#pragma unroll
        for (int j = 0; j < 8; j++) acc[j] = 0.f;

        int kk = 0;
        for (; kk + 8 <= dv; kk += 8) {
            int k0 = kk + grp, k1 = kk + 4 + grp;
            uint32 cp0 = __shfl(colpack, k0 >> 1, 64);
            uint32 cp1 = __shfl(colpack, k1 >> 1, 64);
            int u0 = (k0 & 1) ? (int)(cp0 >> 16) : (int)(cp0 & 0xffffu);
            int u1 = (k1 & 1) ? (int)(cp1 >> 16) : (int)(cp1 & 0xffffu);
            uint4 w0 = *(const uint4*)(gp + (u0 << 6));
            uint4 w1 = *(const uint4*)(gp + (u1 << 6));
            if (SCALED_IN) {
                acc[0] += blo(w0.x); acc[1] += bhi(w0.x);
                acc[2] += blo(w0.y); acc[3] += bhi(w0.y);
                acc[4] += blo(w0.z); acc[5] += bhi(w0.z);
                acc[6] += blo(w0.w); acc[7] += bhi(w0.w);
                acc[0] += blo(w1.x); acc[1] += bhi(w1.x);
                acc[2] += blo(w1.y); acc[3] += bhi(w1.y);
                acc[4] += blo(w1.z); acc[5] += bhi(w1.z);
                acc[6] += blo(w1.w); acc[7] += bhi(w1.w);
            } else {
                float s0 = dis[u0], s1 = dis[u1];
                acc[0] += s0 * blo(w0.x); acc[1] += s0 * bhi(w0.x);
                acc[2] += s0 * blo(w0.y); acc[3] += s0 * bhi(w0.y);
                acc[4] += s0 * blo(w0.z); acc[5] += s0 * bhi(w0.z);
                acc[6] += s0 * blo(w0.w); acc[7] += s0 * bhi(w0.w);
                acc[0] += s1 * blo(w1.x); acc[1] += s1 * bhi(w1.x);
                acc[2] += s1 * blo(w1.y); acc[3] += s1 * bhi(w1.y);
                acc[4] += s1 * blo(w1.z); acc[5] += s1 * bhi(w1.z);
                acc[6] += s1 * blo(w1.w); acc[7] += s1 * bhi(w1.w);
            }
        }
        for (; kk < dv; kk += 4) {
            int k = kk + grp;
            uint32 cp = __shfl(colpack, (k >> 1) & 63, 64);
            int uu = (k & 1) ? (int)(cp >> 16) : (int)(cp & 0xffffu);
            if (k < dv) {
                uint4 w = *(const uint4*)(gp + (uu << 6));
                float s = SCALED_IN ? 1.f : dis[uu];
                acc[0] += s * blo(w.x); acc[1] += s * bhi(w.x);
                acc[2] += s * blo(w.y); acc[3] += s * bhi(w.y);
                acc[4] += s * blo(w.z); acc[5] += s * bhi(w.z);
                acc[6] += s * blo(w.w); acc[7] += s * bhi(w.w);
            }
        }
#pragma unroll
        for (int j = 0; j < 8; j++) {
            acc[j] += __shfl_xor(acc[j], 16, 64);
            acc[j] += __shfl_xor(acc[j], 32, 64);
        }
        float sv = dis[v];
        uint4 hs = *(const uint4*)(gp + (v << 6));
        float fs = SCALED_IN ? 1.f : sv;
        float r0 = sv * (acc[0] + fs * blo(hs.x));
        float r1 = sv * (acc[1] + fs * bhi(hs.x));
        float r2 = sv * (acc[2] + fs * blo(hs.y));
        float r3 = sv * (acc[3] + fs * bhi(hs.y));
        float r4 = sv * (acc[4] + fs * blo(hs.z));
        float r5 = sv * (acc[5] + fs * bhi(hs.z));
        float r6 = sv * (acc[6] + fs * blo(hs.w));
        float r7 = sv * (acc[7] + fs * bhi(hs.w));
        if (grp == 0) {
            float4* o = (float4*)(Xs + vr * DIM + sl * 8);
            o[0] = make_float4(fmaxf(r0, 0.f), fmaxf(r1, 0.f),
                               fmaxf(r2, 0.f), fmaxf(r3, 0.f));
            o[1] = make_float4(fmaxf(r4, 0.f), fmaxf(r5, 0.f),
                               fmaxf(r6, 0.f), fmaxf(r7, 0.f));
        }
    }
}

// ---------------- unit: fused layer (agg + gemm_scale) ----------------
template <bool SCALED_IN>
__device__ __forceinline__ void layer_unit(int u, const ushort16* __restrict__ Gh_in,
                                           const int* __restrict__ deg,
                                           const ushort16* __restrict__ col,
                                           const float* __restrict__ dis,
                                           const float* __restrict__ W,
                                           ushort16* __restrict__ Gh_out,
                                           float* __restrict__ Xs) {
    agg_to_lds<SCALED_IN>(u, Gh_in, deg, col, dis, Xs);
    __syncthreads();

    int c  = threadIdx.x & 127;
    int rg = threadIdx.x >> 7;
    int row0 = u * NPB + rg * 4;
    float acc[4] = {0.f, 0.f, 0.f, 0.f};
    for (int k = 0; k < DIM; k += 4) {
        float w0 = W[(k + 0) * DIM + c];
        float w1 = W[(k + 1) * DIM + c];
        float w2 = W[(k + 2) * DIM + c];
        float w3 = W[(k + 3) * DIM + c];
#pragma unroll
        for (int r = 0; r < 4; r++) {
            float4 xv = *(const float4*)(Xs + (rg * 4 + r) * DIM + k);
            acc[r] += xv.x * w0 + xv.y * w1 + xv.z * w2 + xv.w * w3;
        }
    }
#pragma unroll
    for (int r = 0; r < 4; r++) {
        int row = row0 + r;
        Gh_out[row * DIM + c] = f32_to_bf16_rne(acc[r] * dis[row]);
    }
}

// ---------------- unit: fused last (agg + head + pool) ----------------
__device__ __forceinline__ void last_unit(int u, const ushort16* __restrict__ Gh_in,
                                          const int* __restrict__ deg,
                                          const ushort16* __restrict__ col,
                                          const float* __restrict__ dis,
                                          const int* __restrict__ batch,
                                          const float* __restrict__ fcw,
                                          const float* __restrict__ fcb,
                                          float* __restrict__ xr,
                                          float* __restrict__ out,
                                          float* __restrict__ Xs) {
    agg_to_lds<true>(u, Gh_in, deg, col, dis, Xs);
    __syncthreads();

    int wave = threadIdx.x >> 6;
    int lane = threadIdx.x & 63;
#pragma unroll
    for (int i = 0; i < 2; i++) {
        int vr   = wave * 2 + i;
        int node = u * NPB + vr;
        float xl = Xs[vr * DIM + lane];
        float xh = Xs[vr * DIM + 64 + lane];
        float lg[NCLS];
#pragma unroll
        for (int c2 = 0; c2 < NCLS; c2++) {
            float p = xl * fcw[lane * NCLS + c2] + xh * fcw[(lane + 64) * NCLS + c2];
#pragma unroll
            for (int off = 32; off >= 1; off >>= 1) p += __shfl_xor(p, off, 64);
            lg[c2] = p + fcb[c2];
        }
        float m = lg[0];
#pragma unroll
        for (int c2 = 1; c2 < NCLS; c2++) m = fmaxf(m, lg[c2]);
        float s = 0.f;
#pragma unroll
        for (int c2 = 0; c2 < NCLS; c2++) s += expf(lg[c2] - m);
        float lse = m + logf(s);
        if (lane < NCLS) out[node * NCLS + lane] = lg[lane] - lse;
    }

    if (threadIdx.x < 128) {
        int start = u * NPB;
        int t = threadIdx.x;
        int b = batch[start];
        float a = 0.f;
        for (int n = 0; n < NPB; n++) {
            int bn = batch[start + n];
            if (bn != b) { atomicAdd(&xr[b * DIM + t], a); a = 0.f; b = bn; }
            a += Xs[n * DIM + t];
        }
        atomicAdd(&xr[b * DIM + t], a);
    }
}

// ---------------- persistent cooperative kernel ----------------
__global__ __launch_bounds__(256, 4)
void gcn_all(const int* __restrict__ src, const int* __restrict__ dst,
             int* __restrict__ gcursor, uint32* __restrict__ bins,
             const float* __restrict__ X,
             const float* __restrict__ W1, const float* __restrict__ W2,
             const float* __restrict__ W3, const float* __restrict__ W4,
             ushort16* __restrict__ Gh_a, ushort16* __restrict__ Gh_b,
             const int* __restrict__ batch, const float* __restrict__ fcw,
             const float* __restrict__ fcb, float* __restrict__ xr,
             float* __restrict__ out, int* __restrict__ deg,
             float* __restrict__ dis, ushort16* __restrict__ col) {
    __shared__ AllSh sh;
    __shared__ int unitS;
    int* pc = gcursor + 192;     // phase cursors (zeroed by host memset)
    cg::grid_group grid = cg::this_grid();

    // ---- phase 0: gemm1 (0..624) + binning (625..784) + zero xr (785)
    for (;;) {
        __syncthreads();
        if (threadIdx.x == 0) unitS = atomicAdd(&pc[0], 1);
        __syncthreads();
        int u = unitS;
        if (u >= 786) break;
        if (u < 625)       gemm1_unit(u, X, W1, Gh_a);
        else if (u < 785)  bin_unit(u - 625, src, dst, gcursor, bins, sh.bin);
        else               zero_xr_unit(xr);
    }
    __threadfence();
    grid.sync();

    // ---- phase 1: binB
    for (;;) {
        __syncthreads();
        if (threadIdx.x == 0) unitS = atomicAdd(&pc[1], 1);
        __syncthreads();
        int u = unitS;
        if (u >= NB) break;
        binB_unit(u, gcursor, bins, col, deg, dis, sh.bb);
    }
    __threadfence();
    grid.sync();

    // ---- phase 2: layer 2 (unscaled input)
    for (;;) {
        __syncthreads();
        if (threadIdx.x == 0) unitS = atomicAdd(&pc[2], 1);
        __syncthreads();
        int u = unitS;
        if (u >= NLU) break;
        layer_unit<false>(u, Gh_a, deg, col, dis, W2, Gh_b, sh.ly.Xs);
    }
    __threadfence();
    grid.sync();

    // ---- phase 3: layer 3
    for (;;) {
        __syncthreads();
        if (threadIdx.x == 0) unitS = atomicAdd(&pc[3], 1);
        __syncthreads();
        int u = unitS;
        if (u >= NLU) break;
        layer_unit<true>(u, Gh_b, deg, col, dis, W3, Gh_a, sh.ly.Xs);
    }
    __threadfence();
    grid.sync();

    // ---- phase 4: layer 4
    for (;;) {
        __syncthreads();
        if (threadIdx.x == 0) unitS = atomicAdd(&pc[4], 1);
        __syncthreads();
        int u = unitS;
        if (u >= NLU) break;
        layer_unit<true>(u, Gh_a, deg, col, dis, W4, Gh_b, sh.ly.Xs);
    }
    __threadfence();
    grid.sync();

    // ---- phase 5: last (agg + head + pool)
    for (;;) {
        __syncthreads();
        if (threadIdx.x == 0) unitS = atomicAdd(&pc[5], 1);
        __syncthreads();
        int u = unitS;
        if (u >= NLU) break;
        last_unit(u, Gh_b, deg, col, dis, batch, fcw, fcb, xr, out, sh.ly.Xs);
    }
}

// ---------------- fallback wrappers (non-cooperative path) ----------------
__global__ __launch_bounds__(256) void k_phase0(const int* src, const int* dst,
                                                int* gcursor, uint32* bins,
                                                const float* X, const float* W,
                                                ushort16* Gh, float* xr) {
    __shared__ AllSh sh;
    int u = blockIdx.x;
    if (u < 625)      gemm1_unit(u, X, W, Gh);
    else if (u < 785) bin_unit(u - 625, src, dst, gcursor, bins, sh.bin);
    else              zero_xr_unit(xr);
}

__global__ __launch_bounds__(256) void k_binB(const int* gcursor, const uint32* bins,
                                              ushort16* col, int* deg, float* dis) {
    __shared__ AllSh sh;
    binB_unit(blockIdx.x, gcursor, bins, col, deg, dis, sh.bb);
}

template <bool S>
__global__ __launch_bounds__(256) void k_layer(const ushort16* Gh_in, const int* deg,
                                               const ushort16* col, const float* dis,
                                               const float* W, ushort16* Gh_out) {
    __shared__ LySh sh;
    layer_unit<S>(blockIdx.x, Gh_in, deg, col, dis, W, Gh_out, sh.Xs);
}

__global__ __launch_bounds__(256) void k_last(const ushort16* Gh_in, const int* deg,
                                              const ushort16* col, const float* dis,
                                              const int* batch, const float* fcw,
                                              const float* fcb, float* xr, float* out) {
    __shared__ LySh sh;
    last_unit(blockIdx.x, Gh_in, deg, col, dis, batch, fcw, fcb, xr, out, sh.Xs);
}

// ---------------- launch ----------------

extern "C" void kernel_launch(void* const* d_in, const int* in_sizes, int n_in,
                              void* d_out, int out_size, void* d_ws, size_t ws_size,
                              hipStream_t stream) {
    const float* x     = (const float*)d_in[0];
    const int*   ei    = (const int*)d_in[1];      // [2, E] int32
    const int*   src   = ei;
    const int*   dst   = ei + N_EDGES;
    const int*   batch = (const int*)d_in[2];
    const float* W1    = (const float*)d_in[3];
    const float* W2    = (const float*)d_in[4];
    const float* W3    = (const float*)d_in[5];
    const float* W4    = (const float*)d_in[6];
    const float* fcw   = (const float*)d_in[7];
    const float* fcb   = (const float*)d_in[8];

    float* out_ls = (float*)d_out;                 // [N,10]
    float* out_xr = out_ls + N_NODES * NCLS;       // [64,128]

    // workspace layout (16B-aligned element offsets)
    int*      gcursor = (int*)d_ws;                       // 256 ints (0..156 buckets, 192.. phase cursors)
    int*      deg     = gcursor + 256;                    // 10240 ints
    float*    dis     = (float*)(deg + 10240);            // 10240 floats
    uint32*   bins    = (uint32*)(dis + 10240);           // NB*BCAP uint32 (2.89MB)
    ushort16* col     = (ushort16*)(bins + NB * BCAP);    // NB*64*128 ushorts (2.57MB)
    ushort16* Gh_a    = col + (size_t)NB * 64 * 128;      // N*D bf16
    ushort16* Gh_b    = Gh_a + (size_t)N_NODES * DIM;     // N*D bf16

    hipMemsetAsync(gcursor, 0, 256 * sizeof(int), stream);

    // try the single persistent cooperative kernel
    int occ = 0;
    hipError_t oe = hipOccupancyMaxActiveBlocksPerMultiprocessor(&occ, (const void*)gcn_all, 256, 0);
    int grid = (oe == hipSuccess && occ > 0) ? occ * 256 : 0;
    if (grid > 1024) grid = 1024;

    bool done = false;
    if (grid >= 64) {
        void* args[] = {
            (void*)&src, (void*)&dst, (void*)&gcursor, (void*)&bins, (void*)&x,
            (void*)&W1, (void*)&W2, (void*)&W3, (void*)&W4,
            (void*)&Gh_a, (void*)&Gh_b, (void*)&batch, (void*)&fcw, (void*)&fcb,
            (void*)&out_xr, (void*)&out_ls, (void*)&deg, (void*)&dis, (void*)&col
        };
        hipError_t e = hipLaunchCooperativeKernel((const void*)gcn_all, dim3(grid),
                                                  dim3(256), args, 0, stream);
        done = (e == hipSuccess);
    }

    if (!done) {
        // fallback: proven multi-dispatch path
        k_phase0<<<786, 256, 0, stream>>>(src, dst, gcursor, bins, x, W1, Gh_a, out_xr);
        k_binB  <<<NB, 256, 0, stream>>>(gcursor, bins, col, deg, dis);
        k_layer<false><<<NLU, 256, 0, stream>>>(Gh_a, deg, col, dis, W2, Gh_b);
        k_layer<true> <<<NLU, 256, 0, stream>>>(Gh_b, deg, col, dis, W3, Gh_a);
        k_layer<true> <<<NLU, 256, 0, stream>>>(Gh_a, deg, col, dis, W4, Gh_b);
        k_last        <<<NLU, 256, 0, stream>>>(Gh_b, deg, col, dis, batch, fcw, fcb,
                                                out_xr, out_ls);
    }
}

// Round 4
// 192.959 us; speedup vs baseline: 4.3160x; 4.3160x over previous
//
#include <hip/hip_runtime.h>
#include <math.h>

#define N_NODES 10000
#define N_EDGES 640000
#define DIM     128
#define NCLS    10
#define NGRAPH  64
#define NB      157    // buckets of 64 nodes (dst>>6)
#define BCAP    4608   // bucket capacity; bucket ~Poisson(4076), 8 sigma pad
#define EPB     4000   // edges per bin-block (160 blocks)
#define NPB     8      // nodes per fused-layer block (1250 blocks)

typedef unsigned int uint32;
typedef unsigned short ushort16;

__device__ __forceinline__ ushort16 f32_to_bf16_rne(float f) {
    uint32 u = __float_as_uint(f);
    u = (u + 0x7fffu + ((u >> 16) & 1u)) >> 16;   // round-to-nearest-even
    return (ushort16)u;
}
__device__ __forceinline__ uint32 pack_bf16x2(float lo, float hi) {
    return (uint32)f32_to_bf16_rne(lo) | ((uint32)f32_to_bf16_rne(hi) << 16);
}
__device__ __forceinline__ float blo(uint32 x) { return __uint_as_float(x << 16); }
__device__ __forceinline__ float bhi(uint32 x) { return __uint_as_float(x & 0xffff0000u); }

// ---------------- pass A: edge binning (+ fused layer-1 GEMM + xr zero) ----------------
__global__ __launch_bounds__(256) void binA_gemm1(const int* __restrict__ src,
                                                  const int* __restrict__ dst,
                                                  int* __restrict__ gcursor,
                                                  uint32* __restrict__ bins,
                                                  const float* __restrict__ X,
                                                  const float* __restrict__ W,
                                                  ushort16* __restrict__ Gh,
                                                  float* __restrict__ xr) {
    __shared__ uint32 pk[EPB];
    __shared__ int cntS[NB], offS[NB], curS[NB], gposS[NB];

    if (blockIdx.x < 625) {
        int c    = threadIdx.x & 127;
        int rg   = threadIdx.x >> 7;
        int row0 = blockIdx.x * 16 + rg * 8;
        const float* xb = X + row0 * DIM;
        float acc[8] = {0.f, 0.f, 0.f, 0.f, 0.f, 0.f, 0.f, 0.f};
        for (int k = 0; k < DIM; k += 4) {
            float w0 = W[(k + 0) * DIM + c];
            float w1 = W[(k + 1) * DIM + c];
            float w2 = W[(k + 2) * DIM + c];
            float w3 = W[(k + 3) * DIM + c];
#pragma unroll
            for (int r = 0; r < 8; r++) {
                float4 xv = *(const float4*)(xb + r * DIM + k);
                acc[r] += xv.x * w0 + xv.y * w1 + xv.z * w2 + xv.w * w3;
            }
        }
#pragma unroll
        for (int r = 0; r < 8; r++)
            Gh[(row0 + r) * DIM + c] = f32_to_bf16_rne(acc[r]);
        return;
    }

    if (blockIdx.x == 785) {
        float4 z = make_float4(0.f, 0.f, 0.f, 0.f);
        for (int j = threadIdx.x; j < NGRAPH * DIM / 4; j += 256)
            ((float4*)xr)[j] = z;
        return;
    }

    int ab  = blockIdx.x - 625;     // 0..159
    int tid = threadIdx.x;
    for (int i = tid; i < NB; i += 256) cntS[i] = 0;
    __syncthreads();

    int base = ab * EPB;
    uint32 pr[16];
#pragma unroll
    for (int it = 0; it < 16; it++) {
        int i = it * 256 + tid;
        uint32 p = 0xffffffffu;
        if (i < EPB) {
            int e = base + i;
            p = ((uint32)dst[e] << 16) | (uint32)src[e];
            atomicAdd(&cntS[p >> 22], 1);     // p>>22 == dst>>6
        }
        pr[it] = p;
    }
    __syncthreads();

    // exclusive scan of cntS by wave 0 (3 rounds of 64)
    if (tid < 64) {
        int carry = 0;
        for (int r = 0; r < 3; r++) {
            int idx = r * 64 + tid;
            int v = (idx < NB) ? cntS[idx] : 0;
            int inc = v;
#pragma unroll
            for (int o = 1; o < 64; o <<= 1) {
                int u = __shfl_up(inc, o, 64);
                if (tid >= o) inc += u;
            }
            if (idx < NB) { offS[idx] = inc - v + carry; curS[idx] = inc - v + carry; }
            carry += __shfl(inc, 63, 64);
        }
    }
    __syncthreads();

    // relocate into LDS so global writes are sequential runs
#pragma unroll
    for (int it = 0; it < 16; it++) {
        uint32 p = pr[it];
        if (p != 0xffffffffu) {
            int b = p >> 22;
            pk[atomicAdd(&curS[b], 1)] = p;
        }
    }
    __syncthreads();

    if (tid < NB) gposS[tid] = atomicAdd(&gcursor[tid], cntS[tid]);
    __syncthreads();

#pragma unroll
    for (int it = 0; it < 16; it++) {
        int i = it * 256 + tid;
        if (i < EPB) {
            uint32 u = pk[i];
            int b = u >> 22;
            int gp = gposS[b] + (i - offS[b]);
            if (gp < BCAP) bins[b * BCAP + gp] = u;
        }
    }
}

// ---------------- pass B: bucket -> padded adjacency (2 blocks/bucket) ----------------
// 314 blocks fills the 256-CU grid (157 left 40% idle). Each block scans the
// full bucket run but keeps only its 32-node half; 8 KB LDS tile.
__global__ __launch_bounds__(256) void binB2(const int* __restrict__ gcursor,
                                             const uint32* __restrict__ bins,
                                             ushort16* __restrict__ col,
                                             int* __restrict__ deg,
                                             float* __restrict__ dis) {
    __shared__ ushort16 adj[32 * 128];   // 8 KB
    __shared__ int cnt2[32];
    int b    = blockIdx.x >> 1;
    int half = blockIdx.x & 1;
    int tid  = threadIdx.x;
    if (tid < 32) cnt2[tid] = 0;
    __syncthreads();
    int tc = gcursor[b];
    if (tc > BCAP) tc = BCAP;
    const uint32* bb = bins + b * BCAP;
    for (int i = tid; i < tc; i += 256) {
        uint32 u = bb[i];
        int local = (u >> 16) & 63;
        if ((local >> 5) == half) {
            int l5 = local & 31;
            int r = atomicAdd(&cnt2[l5], 1);
            if (r < 128) adj[(l5 << 7) + r] = (ushort16)(u & 0xffffu);
        }
    }
    __syncthreads();
    uint4* dstp = (uint4*)(col + (size_t)b * 64 * 128 + half * 32 * 128);
    const uint4* srcp = (const uint4*)adj;
    for (int j = tid; j < 512; j += 256) dstp[j] = srcp[j];
    if (tid < 32) {
        int node = b * 64 + half * 32 + tid;   // arrays padded to 10240
        int c = cnt2[tid] < 128 ? cnt2[tid] : 128;
        deg[node] = c;
        dis[node] = rsqrtf((float)c + 1.0f);
    }
}

// ---------------- fused agg (16-lane x 16B gathers, 4 in flight) -> LDS ----------------
template <bool SCALED_IN>
__device__ __forceinline__ void agg_to_lds(const ushort16* __restrict__ Gh,
                                           const int* __restrict__ deg,
                                           const ushort16* __restrict__ col,
                                           const float* __restrict__ dis,
                                           float* __restrict__ Xs) {
    int tid  = threadIdx.x;
    int wave = tid >> 6;
    int lane = tid & 63;
    int grp  = lane >> 4;       // 0..3 : which edge of the 4-per-load
    int sl   = lane & 15;       // 0..15: 16B slice of the 256B row
    const uint32* g32 = (const uint32*)Gh;
    const uint32* gp  = g32 + (sl << 2);   // +sl*16B within a row

#pragma unroll
    for (int i = 0; i < 2; i++) {
        int vr = wave * 2 + i;              // local node 0..7
        int v  = blockIdx.x * NPB + vr;
        int dv = deg[v];
        uint32 colpack = ((const uint32*)(col + ((size_t)v << 7)))[lane];
        float acc[8];
#pragma unroll
        for (int j = 0; j < 8; j++) acc[j] = 0.f;

        int kk = 0;
        for (; kk + 16 <= dv; kk += 16) {
            int k0 = kk + grp, k1 = kk + 4 + grp, k2 = kk + 8 + grp, k3 = kk + 12 + grp;
            uint32 cp0 = __shfl(colpack, k0 >> 1, 64);
            uint32 cp1 = __shfl(colpack, k1 >> 1, 64);
            uint32 cp2 = __shfl(colpack, k2 >> 1, 64);
            uint32 cp3 = __shfl(colpack, k3 >> 1, 64);
            int u0 = (k0 & 1) ? (int)(cp0 >> 16) : (int)(cp0 & 0xffffu);
            int u1 = (k1 & 1) ? (int)(cp1 >> 16) : (int)(cp1 & 0xffffu);
            int u2 = (k2 & 1) ? (int)(cp2 >> 16) : (int)(cp2 & 0xffffu);
            int u3 = (k3 & 1) ? (int)(cp3 >> 16) : (int)(cp3 & 0xffffu);
            uint4 w0 = *(const uint4*)(gp + (u0 << 6));
            uint4 w1 = *(const uint4*)(gp + (u1 << 6));
            uint4 w2 = *(const uint4*)(gp + (u2 << 6));
            uint4 w3 = *(const uint4*)(gp + (u3 << 6));
            if (SCALED_IN) {
                acc[0] += blo(w0.x); acc[1] += bhi(w0.x);
                acc[2] += blo(w0.y); acc[3] += bhi(w0.y);
                acc[4] += blo(w0.z); acc[5] += bhi(w0.z);
                acc[6] += blo(w0.w); acc[7] += bhi(w0.w);
                acc[0] += blo(w1.x); acc[1] += bhi(w1.x);
                acc[2] += blo(w1.y); acc[3] += bhi(w1.y);
                acc[4] += blo(w1.z); acc[5] += bhi(w1.z);
                acc[6] += blo(w1.w); acc[7] += bhi(w1.w);
                acc[0] += blo(w2.x); acc[1] += bhi(w2.x);
                acc[2] += blo(w2.y); acc[3] += bhi(w2.y);
                acc[4] += blo(w2.z); acc[5] += bhi(w2.z);
                acc[6] += blo(w2.w); acc[7] += bhi(w2.w);
                acc[0] += blo(w3.x); acc[1] += bhi(w3.x);
                acc[2] += blo(w3.y); acc[3] += bhi(w3.y);
                acc[4] += blo(w3.z); acc[5] += bhi(w3.z);
                acc[6] += blo(w3.w); acc[7] += bhi(w3.w);
            } else {
                float s0 = dis[u0], s1 = dis[u1], s2 = dis[u2], s3 = dis[u3];
                acc[0] += s0 * blo(w0.x); acc[1] += s0 * bhi(w0.x);
                acc[2] += s0 * blo(w0.y); acc[3] += s0 * bhi(w0.y);
                acc[4] += s0 * blo(w0.z); acc[5] += s0 * bhi(w0.z);
                acc[6] += s0 * blo(w0.w); acc[7] += s0 * bhi(w0.w);
                acc[0] += s1 * blo(w1.x); acc[1] += s1 * bhi(w1.x);
                acc[2] += s1 * blo(w1.y); acc[3] += s1 * bhi(w1.y);
                acc[4] += s1 * blo(w1.z); acc[5] += s1 * bhi(w1.z);
                acc[6] += s1 * blo(w1.w); acc[7] += s1 * bhi(w1.w);
                acc[0] += s2 * blo(w2.x); acc[1] += s2 * bhi(w2.x);
                acc[2] += s2 * blo(w2.y); acc[3] += s2 * bhi(w2.y);
                acc[4] += s2 * blo(w2.z); acc[5] += s2 * bhi(w2.z);
                acc[6] += s2 * blo(w2.w); acc[7] += s2 * bhi(w2.w);
                acc[0] += s3 * blo(w3.x); acc[1] += s3 * bhi(w3.x);
                acc[2] += s3 * blo(w3.y); acc[3] += s3 * bhi(w3.y);
                acc[4] += s3 * blo(w3.z); acc[5] += s3 * bhi(w3.z);
                acc[6] += s3 * blo(w3.w); acc[7] += s3 * bhi(w3.w);
            }
        }
        for (; kk + 8 <= dv; kk += 8) {
            int k0 = kk + grp, k1 = kk + 4 + grp;
            uint32 cp0 = __shfl(colpack, k0 >> 1, 64);
            uint32 cp1 = __shfl(colpack, k1 >> 1, 64);
            int u0 = (k0 & 1) ? (int)(cp0 >> 16) : (int)(cp0 & 0xffffu);
            int u1 = (k1 & 1) ? (int)(cp1 >> 16) : (int)(cp1 & 0xffffu);
            uint4 w0 = *(const uint4*)(gp + (u0 << 6));
            uint4 w1 = *(const uint4*)(gp + (u1 << 6));
            float s0 = SCALED_IN ? 1.f : dis[u0];
            float s1 = SCALED_IN ? 1.f : dis[u1];
            acc[0] += s0 * blo(w0.x); acc[1] += s0 * bhi(w0.x);
            acc[2] += s0 * blo(w0.y); acc[3] += s0 * bhi(w0.y);
            acc[4] += s0 * blo(w0.z); acc[5] += s0 * bhi(w0.z);
            acc[6] += s0 * blo(w0.w); acc[7] += s0 * bhi(w0.w);
            acc[0] += s1 * blo(w1.x); acc[1] += s1 * bhi(w1.x);
            acc[2] += s1 * blo(w1.y); acc[3] += s1 * bhi(w1.y);
            acc[4] += s1 * blo(w1.z); acc[5] += s1 * bhi(w1.z);
            acc[6] += s1 * blo(w1.w); acc[7] += s1 * bhi(w1.w);
        }
        for (; kk < dv; kk += 4) {
            int k = kk + grp;
            uint32 cp = __shfl(colpack, (k >> 1) & 63, 64);
            int u = (k & 1) ? (int)(cp >> 16) : (int)(cp & 0xffffu);
            if (k < dv) {
                uint4 w = *(const uint4*)(gp + (u << 6));
                float s = SCALED_IN ? 1.f : dis[u];
                acc[0] += s * blo(w.x); acc[1] += s * bhi(w.x);
                acc[2] += s * blo(w.y); acc[3] += s * bhi(w.y);
                acc[4] += s * blo(w.z); acc[5] += s * bhi(w.z);
                acc[6] += s * blo(w.w); acc[7] += s * bhi(w.w);
            }
        }
#pragma unroll
        for (int j = 0; j < 8; j++) {
            acc[j] += __shfl_xor(acc[j], 16, 64);
            acc[j] += __shfl_xor(acc[j], 32, 64);
        }
        float sv = dis[v];
        uint4 hs = *(const uint4*)(gp + (v << 6));
        float fs = SCALED_IN ? 1.f : sv;
        float r0 = sv * (acc[0] + fs * blo(hs.x));
        float r1 = sv * (acc[1] + fs * bhi(hs.x));
        float r2 = sv * (acc[2] + fs * blo(hs.y));
        float r3 = sv * (acc[3] + fs * bhi(hs.y));
        float r4 = sv * (acc[4] + fs * blo(hs.z));
        float r5 = sv * (acc[5] + fs * bhi(hs.z));
        float r6 = sv * (acc[6] + fs * blo(hs.w));
        float r7 = sv * (acc[7] + fs * bhi(hs.w));
        if (grp == 0) {
            float4* o = (float4*)(Xs + vr * DIM + sl * 8);
            o[0] = make_float4(fmaxf(r0, 0.f), fmaxf(r1, 0.f),
                               fmaxf(r2, 0.f), fmaxf(r3, 0.f));
            o[1] = make_float4(fmaxf(r4, 0.f), fmaxf(r5, 0.f),
                               fmaxf(r6, 0.f), fmaxf(r7, 0.f));
        }
    }
}

// ---------------- fused layer: agg (LDS) + gemm_scale (col-pair x 4-way K-split) ----
// Each thread: 2 adjacent cols (W as float2), k-quarter by row-group. X broadcast
// LDS wave-reads per block halve vs 2-way split (512 -> 256); GEMM goes VALU-bound.
template <bool SCALED_IN>
__global__ __launch_bounds__(256) void fused_layer(const ushort16* __restrict__ Gh_in,
                                                   const int* __restrict__ deg,
                                                   const ushort16* __restrict__ col,
                                                   const float* __restrict__ dis,
                                                   const float* __restrict__ W,
                                                   ushort16* __restrict__ Gh_out) {
    __shared__ float Xs[NPB * DIM];       // 4 KB
    __shared__ float Cs[3 * NPB * DIM];   // 12 KB partial-C reduction
    agg_to_lds<SCALED_IN>(Gh_in, deg, col, dis, Xs);
    __syncthreads();

    int cp = threadIdx.x & 63;       // col-pair id, cols (2cp, 2cp+1)
    int c0 = cp * 2;
    int rg = threadIdx.x >> 6;       // k-quarter 0..3
    const float* Wq = W + (rg * 32) * DIM;
    const float* Xq = Xs + rg * 32;
    float a0[8] = {0.f,0.f,0.f,0.f,0.f,0.f,0.f,0.f};
    float a1[8] = {0.f,0.f,0.f,0.f,0.f,0.f,0.f,0.f};
    for (int kq = 0; kq < 32; kq += 4) {
        float4 xv[8];
#pragma unroll
        for (int r = 0; r < 8; r++) xv[r] = *(const float4*)(Xq + r * DIM + kq);
#pragma unroll
        for (int dk = 0; dk < 4; dk++) {
            float2 wv = *(const float2*)(Wq + (kq + dk) * DIM + c0);
#pragma unroll
            for (int r = 0; r < 8; r++) {
                float xd = ((const float*)&xv[r])[dk];
                a0[r] += xd * wv.x;
                a1[r] += xd * wv.y;
            }
        }
    }
    if (rg) {
        float2* cs = (float2*)(Cs + (rg - 1) * NPB * DIM);
#pragma unroll
        for (int r = 0; r < 8; r++) cs[r * 64 + cp] = make_float2(a0[r], a1[r]);
    }
    __syncthreads();
    if (rg == 0) {
        uint32* gout = (uint32*)Gh_out;
#pragma unroll
        for (int r = 0; r < 8; r++) {
            float sx = a0[r], sy = a1[r];
#pragma unroll
            for (int q = 0; q < 3; q++) {
                float2 p = ((const float2*)(Cs + q * NPB * DIM))[r * 64 + cp];
                sx += p.x; sy += p.y;
            }
            int row = blockIdx.x * NPB + r;
            float d = dis[row];
            gout[row * 64 + cp] = pack_bf16x2(sx * d, sy * d);
        }
    }
}

// ---------------- fused last: agg (LDS) + head + pool ----------------
__global__ __launch_bounds__(256) void fused_last(const ushort16* __restrict__ Gh_in,
                                                  const int* __restrict__ deg,
                                                  const ushort16* __restrict__ col,
                                                  const float* __restrict__ dis,
                                                  const int* __restrict__ batch,
                                                  const float* __restrict__ fcw,
                                                  const float* __restrict__ fcb,
                                                  float* __restrict__ xr,
                                                  float* __restrict__ out) {
    __shared__ float Xs[NPB * DIM];
    agg_to_lds<true>(Gh_in, deg, col, dis, Xs);
    __syncthreads();

    int wave = threadIdx.x >> 6;
    int lane = threadIdx.x & 63;
#pragma unroll
    for (int i = 0; i < 2; i++) {
        int vr   = wave * 2 + i;
        int node = blockIdx.x * NPB + vr;
        float xl = Xs[vr * DIM + lane];
        float xh = Xs[vr * DIM + 64 + lane];
        float lg[NCLS];
#pragma unroll
        for (int c2 = 0; c2 < NCLS; c2++) {
            float p = xl * fcw[lane * NCLS + c2] + xh * fcw[(lane + 64) * NCLS + c2];
#pragma unroll
            for (int off = 32; off >= 1; off >>= 1) p += __shfl_xor(p, off, 64);
            lg[c2] = p + fcb[c2];
        }
        float m = lg[0];
#pragma unroll
        for (int c2 = 1; c2 < NCLS; c2++) m = fmaxf(m, lg[c2]);
        float s = 0.f;
#pragma unroll
        for (int c2 = 0; c2 < NCLS; c2++) s += expf(lg[c2] - m);
        float lse = m + logf(s);
        if (lane < NCLS) out[node * NCLS + lane] = lg[lane] - lse;
    }

    // pool: batch is sorted, run-length flush (<= ~1 extra flush per block)
    if (threadIdx.x < 128) {
        int start = blockIdx.x * NPB;
        int t = threadIdx.x;
        int b = batch[start];
        float a = 0.f;
        for (int n = 0; n < NPB; n++) {
            int bn = batch[start + n];
            if (bn != b) { atomicAdd(&xr[b * DIM + t], a); a = 0.f; b = bn; }
            a += Xs[n * DIM + t];
        }
        atomicAdd(&xr[b * DIM + t], a);
    }
}

// ---------------- launch ----------------

extern "C" void kernel_launch(void* const* d_in, const int* in_sizes, int n_in,
                              void* d_out, int out_size, void* d_ws, size_t ws_size,
                              hipStream_t stream) {
    const float* x     = (const float*)d_in[0];
    const int*   ei    = (const int*)d_in[1];      // [2, E] int32
    const int*   src   = ei;
    const int*   dst   = ei + N_EDGES;
    const int*   batch = (const int*)d_in[2];
    const float* W[4]  = {(const float*)d_in[3], (const float*)d_in[4],
                          (const float*)d_in[5], (const float*)d_in[6]};
    const float* fcw   = (const float*)d_in[7];
    const float* fcb   = (const float*)d_in[8];

    float* out_ls = (float*)d_out;                 // [N,10]
    float* out_xr = out_ls + N_NODES * NCLS;       // [64,128]

    // workspace layout (16B-aligned element offsets)
    int*      gcursor = (int*)d_ws;                       // 256 ints
    int*      deg     = gcursor + 256;                    // 10240 ints
    float*    dis     = (float*)(deg + 10240);            // 10240 floats
    uint32*   bins    = (uint32*)(dis + 10240);           // NB*BCAP uint32 (2.89MB)
    ushort16* col     = (ushort16*)(bins + NB * BCAP);    // NB*64*128 ushorts (2.57MB)
    ushort16* Gh_a    = col + (size_t)NB * 64 * 128;      // N*D bf16
    ushort16* Gh_b    = Gh_a + (size_t)N_NODES * DIM;     // N*D bf16

    hipMemsetAsync(gcursor, 0, 256 * sizeof(int), stream);

    binA_gemm1<<<786, 256, 0, stream>>>(src, dst, gcursor, bins, x, W[0], Gh_a, out_xr);
    binB2     <<<2 * NB, 256, 0, stream>>>(gcursor, bins, col, deg, dis);

    fused_layer<false><<<N_NODES / NPB, 256, 0, stream>>>(Gh_a, deg, col, dis, W[1], Gh_b);
    fused_layer<true> <<<N_NODES / NPB, 256, 0, stream>>>(Gh_b, deg, col, dis, W[2], Gh_a);
    fused_layer<true> <<<N_NODES / NPB, 256, 0, stream>>>(Gh_a, deg, col, dis, W[3], Gh_b);
    fused_last        <<<N_NODES / NPB, 256, 0, stream>>>(Gh_b, deg, col, dis, batch,
                                                          fcw, fcb, out_xr, out_ls);
}

// Round 5
// 182.154 us; speedup vs baseline: 4.5721x; 1.0593x over previous
//
#include <hip/hip_runtime.h>
#include <hip/hip_fp16.h>
#include <math.h>

#define N_NODES 10000
#define N_EDGES 640000
#define DIM     128
#define NCLS    10
#define NGRAPH  64
#define NB      157    // buckets of 64 nodes (dst>>6)
#define BCAP    4608   // bucket capacity; bucket ~Poisson(4076), 8 sigma pad
#define EPB     4000   // edges per bin-block (160 blocks)
#define NPB     8      // nodes per fused-layer block (1250 blocks)

typedef unsigned int uint32;
typedef unsigned short ushort16;
typedef _Float16 h2v __attribute__((ext_vector_type(2)));

#define SEL_LO 0x00003C00u   // f16x2 (1.0, 0.0)
#define SEL_HI 0x3C000000u   // f16x2 (0.0, 1.0)

__device__ __forceinline__ h2v as_h2(uint32 u) { h2v r; __builtin_memcpy(&r, &u, 4); return r; }

// acc += w.lo*p.lo + w.hi*p.hi  (packed f16 dot2, f32 accumulate)
__device__ __forceinline__ float fd2(uint32 w, uint32 p, float acc) {
#if __has_builtin(__builtin_amdgcn_fdot2)
    return __builtin_amdgcn_fdot2(as_h2(w), as_h2(p), acc, false);
#else
    h2v a = as_h2(w), b = as_h2(p);
    return acc + (float)a[0] * (float)b[0] + (float)a[1] * (float)b[1];
#endif
}
__device__ __forceinline__ float f16lo(uint32 u) { return (float)as_h2(u)[0]; }
__device__ __forceinline__ float f16hi(uint32 u) { return (float)as_h2(u)[1]; }
__device__ __forceinline__ ushort16 f32_f16(float f) {
    return __half_as_ushort(__float2half(f));
}
__device__ __forceinline__ uint32 pack_f16x2(float lo, float hi) {
    __half2 h = __floats2half2_rn(lo, hi);
    uint32 u; __builtin_memcpy(&u, &h, 4); return u;
}

// ---------------- pass A: bin + layer-1 GEMM + xr zero + W2-4 f16 prepack ----------
// Blocks 0..624: g1 = f16(x @ W1) (unscaled). Blocks 625..784: bin 4000 edges
// each. Block 785: zero out_xr. Blocks 786..788: pack W2/W3/W4 into f16-pair
// form for the dot2 GEMMs of later dispatches.
__global__ __launch_bounds__(256) void binA_gemm1(const int* __restrict__ src,
                                                  const int* __restrict__ dst,
                                                  int* __restrict__ gcursor,
                                                  uint32* __restrict__ bins,
                                                  const float* __restrict__ X,
                                                  const float* __restrict__ W,
                                                  const float* __restrict__ W2,
                                                  const float* __restrict__ W3,
                                                  const float* __restrict__ W4,
                                                  uint32* __restrict__ Wp,
                                                  ushort16* __restrict__ Gh,
                                                  float* __restrict__ xr) {
    __shared__ uint32 pk[EPB];
    __shared__ int cntS[NB], offS[NB], curS[NB], gposS[NB];

    if (blockIdx.x < 625) {
        int c    = threadIdx.x & 127;
        int rg   = threadIdx.x >> 7;
        int row0 = blockIdx.x * 16 + rg * 8;
        const float* xb = X + row0 * DIM;
        float acc[8] = {0.f, 0.f, 0.f, 0.f, 0.f, 0.f, 0.f, 0.f};
        for (int k = 0; k < DIM; k += 4) {
            float w0 = W[(k + 0) * DIM + c];
            float w1 = W[(k + 1) * DIM + c];
            float w2 = W[(k + 2) * DIM + c];
            float w3 = W[(k + 3) * DIM + c];
#pragma unroll
            for (int r = 0; r < 8; r++) {
                float4 xv = *(const float4*)(xb + r * DIM + k);
                acc[r] += xv.x * w0 + xv.y * w1 + xv.z * w2 + xv.w * w3;
            }
        }
#pragma unroll
        for (int r = 0; r < 8; r++)
            Gh[(row0 + r) * DIM + c] = f32_f16(acc[r]);
        return;
    }

    if (blockIdx.x >= 786) {
        int w = blockIdx.x - 786;                    // 0..2 -> W2,W3,W4
        const float* Ws = (w == 0) ? W2 : (w == 1) ? W3 : W4;
        uint32* Wd = Wp + w * (64 * DIM);
        for (int i = threadIdx.x; i < 64 * DIM; i += 256) {
            int k2 = i >> 7, c = i & 127;
            Wd[i] = pack_f16x2(Ws[(2 * k2) * DIM + c], Ws[(2 * k2 + 1) * DIM + c]);
        }
        return;
    }

    if (blockIdx.x == 785) {
        float4 z = make_float4(0.f, 0.f, 0.f, 0.f);
        for (int j = threadIdx.x; j < NGRAPH * DIM / 4; j += 256)
            ((float4*)xr)[j] = z;
        return;
    }

    int ab  = blockIdx.x - 625;     // 0..159
    int tid = threadIdx.x;
    for (int i = tid; i < NB; i += 256) cntS[i] = 0;
    __syncthreads();

    int base = ab * EPB;
    uint32 pr[16];
#pragma unroll
    for (int it = 0; it < 16; it++) {
        int i = it * 256 + tid;
        uint32 p = 0xffffffffu;
        if (i < EPB) {
            int e = base + i;
            p = ((uint32)dst[e] << 16) | (uint32)src[e];
            atomicAdd(&cntS[p >> 22], 1);     // p>>22 == dst>>6
        }
        pr[it] = p;
    }
    __syncthreads();

    // exclusive scan of cntS by wave 0 (3 rounds of 64)
    if (tid < 64) {
        int carry = 0;
        for (int r = 0; r < 3; r++) {
            int idx = r * 64 + tid;
            int v = (idx < NB) ? cntS[idx] : 0;
            int inc = v;
#pragma unroll
            for (int o = 1; o < 64; o <<= 1) {
                int u = __shfl_up(inc, o, 64);
                if (tid >= o) inc += u;
            }
            if (idx < NB) { offS[idx] = inc - v + carry; curS[idx] = inc - v + carry; }
            carry += __shfl(inc, 63, 64);
        }
    }
    __syncthreads();

    // relocate into LDS so global writes are sequential runs
#pragma unroll
    for (int it = 0; it < 16; it++) {
        uint32 p = pr[it];
        if (p != 0xffffffffu) {
            int b = p >> 22;
            pk[atomicAdd(&curS[b], 1)] = p;
        }
    }
    __syncthreads();

    if (tid < NB) gposS[tid] = atomicAdd(&gcursor[tid], cntS[tid]);
    __syncthreads();

#pragma unroll
    for (int it = 0; it < 16; it++) {
        int i = it * 256 + tid;
        if (i < EPB) {
            uint32 u = pk[i];
            int b = u >> 22;
            int gp = gposS[b] + (i - offS[b]);
            if (gp < BCAP) bins[b * BCAP + gp] = u;
        }
    }
}

// ---------------- pass B: bucket -> padded adjacency (2 blocks/bucket) ----------------
__global__ __launch_bounds__(256) void binB2(const int* __restrict__ gcursor,
                                             const uint32* __restrict__ bins,
                                             ushort16* __restrict__ col,
                                             int* __restrict__ deg,
                                             float* __restrict__ dis,
                                             uint32* __restrict__ disPh) {
    __shared__ ushort16 adj[32 * 128];   // 8 KB
    __shared__ int cnt2[32];
    int b    = blockIdx.x >> 1;
    int half = blockIdx.x & 1;
    int tid  = threadIdx.x;
    if (tid < 32) cnt2[tid] = 0;
    __syncthreads();
    int tc = gcursor[b];
    if (tc > BCAP) tc = BCAP;
    const uint32* bb = bins + b * BCAP;
    for (int i = tid; i < tc; i += 256) {
        uint32 u = bb[i];
        int local = (u >> 16) & 63;
        if ((local >> 5) == half) {
            int l5 = local & 31;
            int r = atomicAdd(&cnt2[l5], 1);
            if (r < 128) adj[(l5 << 7) + r] = (ushort16)(u & 0xffffu);
        }
    }
    __syncthreads();
    uint4* dstp = (uint4*)(col + (size_t)b * 64 * 128 + half * 32 * 128);
    const uint4* srcp = (const uint4*)adj;
    for (int j = tid; j < 512; j += 256) dstp[j] = srcp[j];
    if (tid < 32) {
        int node = b * 64 + half * 32 + tid;   // arrays padded to 10240
        int c = cnt2[tid] < 128 ? cnt2[tid] : 128;
        float dv = rsqrtf((float)c + 1.0f);
        deg[node] = c;
        dis[node] = dv;
        disPh[node] = (uint32)__half_as_ushort(__float2half(dv));  // (f16(dis), 0)
    }
}

// ---------------- fused agg via packed-f16 dot2 -> LDS ----------------
// 16 lanes x 16B per edge row; 4 edges per wave-load. Accumulate with
// v_dot2_f32_f16: 2 MACs/inst (halves agg VALU vs unpack+add). The one
// scaled layer multiplies by f16(dis[u]) through the dot2 operand.
template <bool SCALED_IN, bool PACK_OUT>
__device__ __forceinline__ void agg_to_lds(const ushort16* __restrict__ Gh,
                                           const int* __restrict__ deg,
                                           const ushort16* __restrict__ col,
                                           const float* __restrict__ dis,
                                           const uint32* __restrict__ disPh,
                                           void* __restrict__ Xout) {
    int tid  = threadIdx.x;
    int wave = tid >> 6;
    int lane = tid & 63;
    int grp  = lane >> 4;       // 0..3 : which edge of the 4-per-load
    int sl   = lane & 15;       // 0..15: 16B slice of the 256B row
    const uint32* g32 = (const uint32*)Gh;
    const uint32* gp  = g32 + (sl << 2);   // +sl*16B within a row

#pragma unroll
    for (int i = 0; i < 2; i++) {
        int vr = wave * 2 + i;              // local node 0..7
        int v  = blockIdx.x * NPB + vr;
        int dv = deg[v];
        uint32 colpack = ((const uint32*)(col + ((size_t)v << 7)))[lane];
        float acc[8];
#pragma unroll
        for (int j = 0; j < 8; j++) acc[j] = 0.f;

        int kk = 0;
        for (; kk + 16 <= dv; kk += 16) {
            int k0 = kk + grp, k1 = kk + 4 + grp, k2 = kk + 8 + grp, k3 = kk + 12 + grp;
            uint32 cp0 = __shfl(colpack, k0 >> 1, 64);
            uint32 cp1 = __shfl(colpack, k1 >> 1, 64);
            uint32 cp2 = __shfl(colpack, k2 >> 1, 64);
            uint32 cp3 = __shfl(colpack, k3 >> 1, 64);
            int u0 = (k0 & 1) ? (int)(cp0 >> 16) : (int)(cp0 & 0xffffu);
            int u1 = (k1 & 1) ? (int)(cp1 >> 16) : (int)(cp1 & 0xffffu);
            int u2 = (k2 & 1) ? (int)(cp2 >> 16) : (int)(cp2 & 0xffffu);
            int u3 = (k3 & 1) ? (int)(cp3 >> 16) : (int)(cp3 & 0xffffu);
            uint4 w0 = *(const uint4*)(gp + (u0 << 6));
            uint4 w1 = *(const uint4*)(gp + (u1 << 6));
            uint4 w2 = *(const uint4*)(gp + (u2 << 6));
            uint4 w3 = *(const uint4*)(gp + (u3 << 6));
            if (SCALED_IN) {
                acc[0] = fd2(w0.x, SEL_LO, acc[0]); acc[1] = fd2(w0.x, SEL_HI, acc[1]);
                acc[2] = fd2(w0.y, SEL_LO, acc[2]); acc[3] = fd2(w0.y, SEL_HI, acc[3]);
                acc[4] = fd2(w0.z, SEL_LO, acc[4]); acc[5] = fd2(w0.z, SEL_HI, acc[5]);
                acc[6] = fd2(w0.w, SEL_LO, acc[6]); acc[7] = fd2(w0.w, SEL_HI, acc[7]);
                acc[0] = fd2(w1.x, SEL_LO, acc[0]); acc[1] = fd2(w1.x, SEL_HI, acc[1]);
                acc[2] = fd2(w1.y, SEL_LO, acc[2]); acc[3] = fd2(w1.y, SEL_HI, acc[3]);
                acc[4] = fd2(w1.z, SEL_LO, acc[4]); acc[5] = fd2(w1.z, SEL_HI, acc[5]);
                acc[6] = fd2(w1.w, SEL_LO, acc[6]); acc[7] = fd2(w1.w, SEL_HI, acc[7]);
                acc[0] = fd2(w2.x, SEL_LO, acc[0]); acc[1] = fd2(w2.x, SEL_HI, acc[1]);
                acc[2] = fd2(w2.y, SEL_LO, acc[2]); acc[3] = fd2(w2.y, SEL_HI, acc[3]);
                acc[4] = fd2(w2.z, SEL_LO, acc[4]); acc[5] = fd2(w2.z, SEL_HI, acc[5]);
                acc[6] = fd2(w2.w, SEL_LO, acc[6]); acc[7] = fd2(w2.w, SEL_HI, acc[7]);
                acc[0] = fd2(w3.x, SEL_LO, acc[0]); acc[1] = fd2(w3.x, SEL_HI, acc[1]);
                acc[2] = fd2(w3.y, SEL_LO, acc[2]); acc[3] = fd2(w3.y, SEL_HI, acc[3]);
                acc[4] = fd2(w3.z, SEL_LO, acc[4]); acc[5] = fd2(w3.z, SEL_HI, acc[5]);
                acc[6] = fd2(w3.w, SEL_LO, acc[6]); acc[7] = fd2(w3.w, SEL_HI, acc[7]);
            } else {
                uint32 dp0 = disPh[u0], dp1 = disPh[u1], dp2 = disPh[u2], dp3 = disPh[u3];
                uint32 dq0 = dp0 << 16, dq1 = dp1 << 16, dq2 = dp2 << 16, dq3 = dp3 << 16;
                acc[0] = fd2(w0.x, dp0, acc[0]); acc[1] = fd2(w0.x, dq0, acc[1]);
                acc[2] = fd2(w0.y, dp0, acc[2]); acc[3] = fd2(w0.y, dq0, acc[3]);
                acc[4] = fd2(w0.z, dp0, acc[4]); acc[5] = fd2(w0.z, dq0, acc[5]);
                acc[6] = fd2(w0.w, dp0, acc[6]); acc[7] = fd2(w0.w, dq0, acc[7]);
                acc[0] = fd2(w1.x, dp1, acc[0]); acc[1] = fd2(w1.x, dq1, acc[1]);
                acc[2] = fd2(w1.y, dp1, acc[2]); acc[3] = fd2(w1.y, dq1, acc[3]);
                acc[4] = fd2(w1.z, dp1, acc[4]); acc[5] = fd2(w1.z, dq1, acc[5]);
                acc[6] = fd2(w1.w, dp1, acc[6]); acc[7] = fd2(w1.w, dq1, acc[7]);
                acc[0] = fd2(w2.x, dp2, acc[0]); acc[1] = fd2(w2.x, dq2, acc[1]);
                acc[2] = fd2(w2.y, dp2, acc[2]); acc[3] = fd2(w2.y, dq2, acc[3]);
                acc[4] = fd2(w2.z, dp2, acc[4]); acc[5] = fd2(w2.z, dq2, acc[5]);
                acc[6] = fd2(w2.w, dp2, acc[6]); acc[7] = fd2(w2.w, dq2, acc[7]);
                acc[0] = fd2(w3.x, dp3, acc[0]); acc[1] = fd2(w3.x, dq3, acc[1]);
                acc[2] = fd2(w3.y, dp3, acc[2]); acc[3] = fd2(w3.y, dq3, acc[3]);
                acc[4] = fd2(w3.z, dp3, acc[4]); acc[5] = fd2(w3.z, dq3, acc[5]);
                acc[6] = fd2(w3.w, dp3, acc[6]); acc[7] = fd2(w3.w, dq3, acc[7]);
            }
        }
        for (; kk + 8 <= dv; kk += 8) {
            int k0 = kk + grp, k1 = kk + 4 + grp;
            uint32 cp0 = __shfl(colpack, k0 >> 1, 64);
            uint32 cp1 = __shfl(colpack, k1 >> 1, 64);
            int u0 = (k0 & 1) ? (int)(cp0 >> 16) : (int)(cp0 & 0xffffu);
            int u1 = (k1 & 1) ? (int)(cp1 >> 16) : (int)(cp1 & 0xffffu);
            uint4 w0 = *(const uint4*)(gp + (u0 << 6));
            uint4 w1 = *(const uint4*)(gp + (u1 << 6));
            uint32 dp0 = SCALED_IN ? SEL_LO : disPh[u0];
            uint32 dp1 = SCALED_IN ? SEL_LO : disPh[u1];
            uint32 dq0 = SCALED_IN ? SEL_HI : (dp0 << 16);
            uint32 dq1 = SCALED_IN ? SEL_HI : (dp1 << 16);
            acc[0] = fd2(w0.x, dp0, acc[0]); acc[1] = fd2(w0.x, dq0, acc[1]);
            acc[2] = fd2(w0.y, dp0, acc[2]); acc[3] = fd2(w0.y, dq0, acc[3]);
            acc[4] = fd2(w0.z, dp0, acc[4]); acc[5] = fd2(w0.z, dq0, acc[5]);
            acc[6] = fd2(w0.w, dp0, acc[6]); acc[7] = fd2(w0.w, dq0, acc[7]);
            acc[0] = fd2(w1.x, dp1, acc[0]); acc[1] = fd2(w1.x, dq1, acc[1]);
            acc[2] = fd2(w1.y, dp1, acc[2]); acc[3] = fd2(w1.y, dq1, acc[3]);
            acc[4] = fd2(w1.z, dp1, acc[4]); acc[5] = fd2(w1.z, dq1, acc[5]);
            acc[6] = fd2(w1.w, dp1, acc[6]); acc[7] = fd2(w1.w, dq1, acc[7]);
        }
        for (; kk < dv; kk += 4) {
            int k = kk + grp;
            uint32 cp = __shfl(colpack, (k >> 1) & 63, 64);
            int u = (k & 1) ? (int)(cp >> 16) : (int)(cp & 0xffffu);
            if (k < dv) {
                uint4 w = *(const uint4*)(gp + (u << 6));
                uint32 dp = SCALED_IN ? SEL_LO : disPh[u];
                uint32 dq = SCALED_IN ? SEL_HI : (dp << 16);
                acc[0] = fd2(w.x, dp, acc[0]); acc[1] = fd2(w.x, dq, acc[1]);
                acc[2] = fd2(w.y, dp, acc[2]); acc[3] = fd2(w.y, dq, acc[3]);
                acc[4] = fd2(w.z, dp, acc[4]); acc[5] = fd2(w.z, dq, acc[5]);
                acc[6] = fd2(w.w, dp, acc[6]); acc[7] = fd2(w.w, dq, acc[7]);
            }
        }
#pragma unroll
        for (int j = 0; j < 8; j++) {
            acc[j] += __shfl_xor(acc[j], 16, 64);
            acc[j] += __shfl_xor(acc[j], 32, 64);
        }
        float sv = dis[v];
        uint4 hs = *(const uint4*)(gp + (v << 6));
        float fs = SCALED_IN ? 1.f : sv;
        float r0 = sv * (acc[0] + fs * f16lo(hs.x));
        float r1 = sv * (acc[1] + fs * f16hi(hs.x));
        float r2 = sv * (acc[2] + fs * f16lo(hs.y));
        float r3 = sv * (acc[3] + fs * f16hi(hs.y));
        float r4 = sv * (acc[4] + fs * f16lo(hs.z));
        float r5 = sv * (acc[5] + fs * f16hi(hs.z));
        float r6 = sv * (acc[6] + fs * f16lo(hs.w));
        float r7 = sv * (acc[7] + fs * f16hi(hs.w));
        if (grp == 0) {
            if (PACK_OUT) {
                uint32* o = (uint32*)Xout + vr * 64 + sl * 4;
                uint4 pk4;
                pk4.x = pack_f16x2(fmaxf(r0, 0.f), fmaxf(r1, 0.f));
                pk4.y = pack_f16x2(fmaxf(r2, 0.f), fmaxf(r3, 0.f));
                pk4.z = pack_f16x2(fmaxf(r4, 0.f), fmaxf(r5, 0.f));
                pk4.w = pack_f16x2(fmaxf(r6, 0.f), fmaxf(r7, 0.f));
                *(uint4*)o = pk4;
            } else {
                float4* o = (float4*)((float*)Xout + vr * DIM + sl * 8);
                o[0] = make_float4(fmaxf(r0, 0.f), fmaxf(r1, 0.f),
                                   fmaxf(r2, 0.f), fmaxf(r3, 0.f));
                o[1] = make_float4(fmaxf(r4, 0.f), fmaxf(r5, 0.f),
                                   fmaxf(r6, 0.f), fmaxf(r7, 0.f));
            }
        }
    }
}

// ---------------- fused layer: dot2-agg (packed LDS) + dot2-GEMM ----------------
template <bool SCALED_IN>
__global__ __launch_bounds__(256) void fused_layer(const ushort16* __restrict__ Gh_in,
                                                   const int* __restrict__ deg,
                                                   const ushort16* __restrict__ col,
                                                   const float* __restrict__ dis,
                                                   const uint32* __restrict__ disPh,
                                                   const uint32* __restrict__ Wp,
                                                   ushort16* __restrict__ Gh_out) {
    __shared__ __align__(16) uint32 Xh[NPB * 64];   // 2 KB packed f16 pairs
    agg_to_lds<SCALED_IN, true>(Gh_in, deg, col, dis, disPh, Xh);
    __syncthreads();

    int c  = threadIdx.x & 127;
    int rg = threadIdx.x >> 7;
    int row0 = blockIdx.x * NPB + rg * 4;
    const uint4* Xh4 = (const uint4*)Xh;
    float acc[4] = {0.f, 0.f, 0.f, 0.f};
    for (int q = 0; q < 16; q++) {
        uint32 wp0 = Wp[(4 * q + 0) * DIM + c];
        uint32 wp1 = Wp[(4 * q + 1) * DIM + c];
        uint32 wp2 = Wp[(4 * q + 2) * DIM + c];
        uint32 wp3 = Wp[(4 * q + 3) * DIM + c];
#pragma unroll
        for (int r = 0; r < 4; r++) {
            uint4 xv = Xh4[(rg * 4 + r) * 16 + q];
            acc[r] = fd2(xv.x, wp0, acc[r]);
            acc[r] = fd2(xv.y, wp1, acc[r]);
            acc[r] = fd2(xv.z, wp2, acc[r]);
            acc[r] = fd2(xv.w, wp3, acc[r]);
        }
    }
#pragma unroll
    for (int r = 0; r < 4; r++) {
        int row = row0 + r;
        Gh_out[row * DIM + c] = f32_f16(acc[r] * dis[row]);
    }
}

// ---------------- fused last: dot2-agg (f32 LDS) + head + pool ----------------
__global__ __launch_bounds__(256) void fused_last(const ushort16* __restrict__ Gh_in,
                                                  const int* __restrict__ deg,
                                                  const ushort16* __restrict__ col,
                                                  const float* __restrict__ dis,
                                                  const uint32* __restrict__ disPh,
                                                  const int* __restrict__ batch,
                                                  const float* __restrict__ fcw,
                                                  const float* __restrict__ fcb,
                                                  float* __restrict__ xr,
                                                  float* __restrict__ out) {
    __shared__ float Xs[NPB * DIM];
    agg_to_lds<true, false>(Gh_in, deg, col, dis, disPh, Xs);
    __syncthreads();

    int wave = threadIdx.x >> 6;
    int lane = threadIdx.x & 63;
#pragma unroll
    for (int i = 0; i < 2; i++) {
        int vr   = wave * 2 + i;
        int node = blockIdx.x * NPB + vr;
        float xl = Xs[vr * DIM + lane];
        float xh = Xs[vr * DIM + 64 + lane];
        float lg[NCLS];
#pragma unroll
        for (int c2 = 0; c2 < NCLS; c2++) {
            float p = xl * fcw[lane * NCLS + c2] + xh * fcw[(lane + 64) * NCLS + c2];
#pragma unroll
            for (int off = 32; off >= 1; off >>= 1) p += __shfl_xor(p, off, 64);
            lg[c2] = p + fcb[c2];
        }
        float m = lg[0];
#pragma unroll
        for (int c2 = 1; c2 < NCLS; c2++) m = fmaxf(m, lg[c2]);
        float s = 0.f;
#pragma unroll
        for (int c2 = 0; c2 < NCLS; c2++) s += expf(lg[c2] - m);
        float lse = m + logf(s);
        if (lane < NCLS) out[node * NCLS + lane] = lg[lane] - lse;
    }

    // pool: batch is sorted, run-length flush (<= ~1 extra flush per block)
    if (threadIdx.x < 128) {
        int start = blockIdx.x * NPB;
        int t = threadIdx.x;
        int b = batch[start];
        float a = 0.f;
        for (int n = 0; n < NPB; n++) {
            int bn = batch[start + n];
            if (bn != b) { atomicAdd(&xr[b * DIM + t], a); a = 0.f; b = bn; }
            a += Xs[n * DIM + t];
        }
        atomicAdd(&xr[b * DIM + t], a);
    }
}

// ---------------- launch ----------------

extern "C" void kernel_launch(void* const* d_in, const int* in_sizes, int n_in,
                              void* d_out, int out_size, void* d_ws, size_t ws_size,
                              hipStream_t stream) {
    const float* x     = (const float*)d_in[0];
    const int*   ei    = (const int*)d_in[1];      // [2, E] int32
    const int*   src   = ei;
    const int*   dst   = ei + N_EDGES;
    const int*   batch = (const int*)d_in[2];
    const float* W1    = (const float*)d_in[3];
    const float* W2    = (const float*)d_in[4];
    const float* W3    = (const float*)d_in[5];
    const float* W4    = (const float*)d_in[6];
    const float* fcw   = (const float*)d_in[7];
    const float* fcb   = (const float*)d_in[8];

    float* out_ls = (float*)d_out;                 // [N,10]
    float* out_xr = out_ls + N_NODES * NCLS;       // [64,128]

    // workspace layout (16B-aligned element offsets)
    int*      gcursor = (int*)d_ws;                       // 256 ints
    int*      deg     = gcursor + 256;                    // 10240 ints
    float*    dis     = (float*)(deg + 10240);            // 10240 floats
    uint32*   bins    = (uint32*)(dis + 10240);           // NB*BCAP uint32 (2.89MB)
    ushort16* col     = (ushort16*)(bins + NB * BCAP);    // NB*64*128 ushorts (2.57MB)
    ushort16* Gh_a    = col + (size_t)NB * 64 * 128;      // N*D f16
    ushort16* Gh_b    = Gh_a + (size_t)N_NODES * DIM;     // N*D f16
    uint32*   Wp      = (uint32*)(Gh_b + (size_t)N_NODES * DIM); // 3*64*128 f16-pairs
    uint32*   disPh   = Wp + 3 * 64 * DIM;                // 10240 packed (f16,0)

    hipMemsetAsync(gcursor, 0, 256 * sizeof(int), stream);

    binA_gemm1<<<789, 256, 0, stream>>>(src, dst, gcursor, bins, x, W1,
                                        W2, W3, W4, Wp, Gh_a, out_xr);
    binB2     <<<2 * NB, 256, 0, stream>>>(gcursor, bins, col, deg, dis, disPh);

    fused_layer<false><<<N_NODES / NPB, 256, 0, stream>>>(Gh_a, deg, col, dis, disPh,
                                                          Wp, Gh_b);
    fused_layer<true> <<<N_NODES / NPB, 256, 0, stream>>>(Gh_b, deg, col, dis, disPh,
                                                          Wp + 64 * DIM, Gh_a);
    fused_layer<true> <<<N_NODES / NPB, 256, 0, stream>>>(Gh_a, deg, col, dis, disPh,
                                                          Wp + 2 * 64 * DIM, Gh_b);
    fused_last        <<<N_NODES / NPB, 256, 0, stream>>>(Gh_b, deg, col, dis, disPh,
                                                          batch, fcw, fcb, out_xr, out_ls);
}